// Round 1
// baseline (331.461 us; speedup 1.0000x reference)
//
#include <hip/hip_runtime.h>
#include <math.h>

// Fused Bayesian-logistic-regression sampling kernel.
// out[i,s] = sigmoid( sqrt(sum_j X_ij^2 * exp(lv_j)) * z_s + sum_j X_ij * mu_j )
//
// Layout: 16 lanes cooperate on one row (D=64 -> one float4 per lane).
// Memory-bound problem: 128 MB read (X) + 256 MB write (out) -> ~61 us floor.

__global__ __launch_bounds__(256) void logreg_sample_kernel(
    const float* __restrict__ X,
    const float* __restrict__ w_mu,
    const float* __restrict__ w_lv,
    const float* __restrict__ z,
    float* __restrict__ out,
    int n_rows)
{
    const int tid   = blockIdx.x * blockDim.x + threadIdx.x;
    const int row   = tid >> 4;     // 16 lanes per row
    const int l     = tid & 15;     // lane within group (aligned inside wave)
    if (row >= n_rows) return;

    // Row-invariant per-lane constants: this lane's 4-column slice of the
    // weights. exp(w_log_var) computed once per thread, not per row.
    const float4 mu4 = ((const float4*)w_mu)[l];
    const float4 lv4 = ((const float4*)w_lv)[l];
    const float4 ev4 = make_float4(__expf(lv4.x), __expf(lv4.y),
                                   __expf(lv4.z), __expf(lv4.w));
    // This lane's 8 z-samples: columns [4l, 4l+4) and [64+4l, 64+4l+4)
    const float4 z0 = ((const float4*)z)[l];
    const float4 z1 = ((const float4*)z)[16 + l];

    // Coalesced 16B/lane read of X: group covers 256 B (one row), wave 1 KB.
    const float4 x4 = ((const float4*)X)[row * 16 + l];

    float a = x4.x * mu4.x + x4.y * mu4.y + x4.z * mu4.z + x4.w * mu4.w;
    float b = x4.x * x4.x * ev4.x + x4.y * x4.y * ev4.y
            + x4.z * x4.z * ev4.z + x4.w * x4.w * ev4.w;

    // Butterfly reduction across the 16-lane group; masks 1..8 never cross
    // the aligned 16-lane boundary, result lands in every lane.
    #pragma unroll
    for (int m = 1; m < 16; m <<= 1) {
        a += __shfl_xor(a, m, 64);
        b += __shfl_xor(b, m, 64);
    }
    const float mean = a;
    const float stdv = sqrtf(b);

    // sigmoid(t) = 1/(1+exp(-t)); saturates correctly at +-inf.
    float4 o0, o1;
    o0.x = 1.0f / (1.0f + __expf(-(stdv * z0.x + mean)));
    o0.y = 1.0f / (1.0f + __expf(-(stdv * z0.y + mean)));
    o0.z = 1.0f / (1.0f + __expf(-(stdv * z0.z + mean)));
    o0.w = 1.0f / (1.0f + __expf(-(stdv * z0.w + mean)));
    o1.x = 1.0f / (1.0f + __expf(-(stdv * z1.x + mean)));
    o1.y = 1.0f / (1.0f + __expf(-(stdv * z1.y + mean)));
    o1.z = 1.0f / (1.0f + __expf(-(stdv * z1.z + mean)));
    o1.w = 1.0f / (1.0f + __expf(-(stdv * z1.w + mean)));

    // Two contiguous-256B-per-group stores: cols [4l,4l+4) and [64+4l,...).
    float4* orow = (float4*)(out + (size_t)row * 128);
    orow[l]      = o0;
    orow[16 + l] = o1;
}

extern "C" void kernel_launch(void* const* d_in, const int* in_sizes, int n_in,
                              void* d_out, int out_size, void* d_ws, size_t ws_size,
                              hipStream_t stream) {
    const float* X    = (const float*)d_in[0];
    const float* w_mu = (const float*)d_in[1];
    const float* w_lv = (const float*)d_in[2];
    const float* z    = (const float*)d_in[3];
    float* out = (float*)d_out;

    const int n_rows = in_sizes[0] / 64;          // 500000
    const int total_threads = n_rows * 16;        // 16 lanes per row
    const int blocks = (total_threads + 255) / 256;

    logreg_sample_kernel<<<blocks, 256, 0, stream>>>(X, w_mu, w_lv, z, out, n_rows);
}